// Round 2
// baseline (207.487 us; speedup 1.0000x reference)
//
#include <hip/hip_runtime.h>
#include <hip/hip_bf16.h>
#include <math.h>

typedef float f32x4 __attribute__((ext_vector_type(4)));
typedef short s16x8 __attribute__((ext_vector_type(8)));

#define NB 2
#define NS 2048
#define NH 16
#define ND 64
#define QTILE 128
#define KVB 64

__device__ __forceinline__ unsigned short f2bf(float f) {
    union { float f; unsigned u; } c; c.f = f;
    return (unsigned short)((c.u + 0x7FFFu + ((c.u >> 16) & 1u)) >> 16);
}

// Flash attention, non-causal. B=2,S=2048,H=16,D=64, fp32 in/out.
// One block = one (b,h) x 128 q-rows. 4 waves, each wave owns 32 q-rows.
// K tile row-major in LDS (swizzled); V tile transposed in LDS (swizzled);
// P goes through per-wave LDS region to re-shape C-frag -> A-frag.
// v2: T14 async-STAGE split — global loads for tile t+1 issue into registers
// before compute of tile t; convert+ds_write lands between the barriers.
__global__ __launch_bounds__(256, 2)
void usp_attn(const float* __restrict__ Qg, const float* __restrict__ Kg,
              const float* __restrict__ Vg, float* __restrict__ Og) {
    __shared__ unsigned short Klds[64 * 64];        // [kv][d]   swz: d ^ ((kv&7)<<3)
    __shared__ unsigned short Vt[64 * 64];          // [d][kv]   swz: kv ^ (((d>>1)&7)<<3)
    __shared__ unsigned short Plds[4 * 32 * 64];    // per-wave [r][kv] swz: kv ^ ((r&7)<<3)

    const int tid  = threadIdx.x;
    const int w    = tid >> 6;     // wave 0..3
    const int lane = tid & 63;
    const int g    = lane >> 4;    // 0..3
    const int x    = lane & 15;

    // XCD-chunked swizzle: 512 blocks, 8 XCDs -> 64 consecutive wgs per XCD
    // = all 16 q-tiles of 4 heads -> K/V stay in that XCD's L2.
    int bid = blockIdx.x;
    int wg  = (bid & 7) * 64 + (bid >> 3);
    int qt  = wg & 15;
    int bh  = wg >> 4;            // 0..31
    int b   = bh >> 4;
    int h   = bh & 15;
    int q0  = qt * QTILE;

    const int srow = NH * ND;     // 1024 floats between consecutive s
    const size_t base = ((size_t)b * NS * NH + h) * ND;

    // ---- Q fragments in registers, scaled by 1/8 (exact in bf16) ----
    // A-frag: row = lane&15, k = 8*(lane>>4)+j  (K=32 per mfma, 2 k-steps over D=64)
    s16x8 qf[2][2];
#pragma unroll
    for (int mt = 0; mt < 2; ++mt) {
        int qr = q0 + w * 32 + mt * 16 + x;
        const float* qp = Qg + base + (size_t)qr * srow;
#pragma unroll
        for (int ks = 0; ks < 2; ++ks) {
            int d0 = ks * 32 + g * 8;
            f32x4 a = *(const f32x4*)(qp + d0);
            f32x4 c = *(const f32x4*)(qp + d0 + 4);
            s16x8 r;
            r[0] = (short)f2bf(a[0] * 0.125f);
            r[1] = (short)f2bf(a[1] * 0.125f);
            r[2] = (short)f2bf(a[2] * 0.125f);
            r[3] = (short)f2bf(a[3] * 0.125f);
            r[4] = (short)f2bf(c[0] * 0.125f);
            r[5] = (short)f2bf(c[1] * 0.125f);
            r[6] = (short)f2bf(c[2] * 0.125f);
            r[7] = (short)f2bf(c[3] * 0.125f);
            qf[mt][ks] = r;
        }
    }

    f32x4 oacc[2][4];
    float mrun[2][4], lrun[2][4];
#pragma unroll
    for (int mt = 0; mt < 2; ++mt)
#pragma unroll
        for (int i = 0; i < 4; ++i) {
            oacc[mt][i] = f32x4{0.f, 0.f, 0.f, 0.f};
            mrun[mt][i] = -INFINITY;
            lrun[mt][i] = 0.f;
        }

    const int sub = tid >> 4;         // staging: kv sub-row 0..15
    const int c4  = (tid & 15) * 4;   // staging: d column (float4)
    const float* kbase = Kg + base + (size_t)sub * srow + c4;
    const float* vbase = Vg + base + (size_t)sub * srow + c4;

    // ---- prologue: load tile 0 into registers ----
    f32x4 kreg[4], vreg[4];
#pragma unroll
    for (int p = 0; p < 4; ++p) {
        kreg[p] = *(const f32x4*)(kbase + (size_t)(p * 16) * srow);
        vreg[p] = *(const f32x4*)(vbase + (size_t)(p * 16) * srow);
    }

    for (int t0 = 0; t0 < NS; t0 += KVB) {
        __syncthreads();   // previous tile fully consumed before overwrite
        // ---- write staged regs -> LDS: K row-major, V transposed, fp32->bf16 ----
#pragma unroll
        for (int p = 0; p < 4; ++p) {
            int kv = sub + p * 16;
            f32x4 kd = kreg[p];
            f32x4 vd = vreg[p];
            int de = c4 ^ ((kv & 7) << 3);
            unsigned lo = (unsigned)f2bf(kd[0]) | ((unsigned)f2bf(kd[1]) << 16);
            unsigned hi = (unsigned)f2bf(kd[2]) | ((unsigned)f2bf(kd[3]) << 16);
            *(uint2*)(&Klds[kv * 64 + de]) = uint2{lo, hi};
#pragma unroll
            for (int i = 0; i < 4; ++i) {
                int d = c4 + i;
                Vt[d * 64 + (kv ^ (((d >> 1) & 7) << 3))] = f2bf(vd[i]);
            }
        }
        __syncthreads();

        // ---- issue next tile's global loads early (hide under compute) ----
        if (t0 + KVB < NS) {
            size_t off = (size_t)(t0 + KVB) * srow;
#pragma unroll
            for (int p = 0; p < 4; ++p) {
                kreg[p] = *(const f32x4*)(kbase + off + (size_t)(p * 16) * srow);
                vreg[p] = *(const f32x4*)(vbase + off + (size_t)(p * 16) * srow);
            }
        }

        // ---- S = (Q/8) K^T : 16 MFMA ----
        f32x4 sc[2][4];
#pragma unroll
        for (int mt = 0; mt < 2; ++mt)
#pragma unroll
            for (int nt = 0; nt < 4; ++nt) sc[mt][nt] = f32x4{0.f, 0.f, 0.f, 0.f};
#pragma unroll
        for (int nt = 0; nt < 4; ++nt) {
            int kv = x + nt * 16;
#pragma unroll
            for (int ks = 0; ks < 2; ++ks) {
                int de = (ks * 32 + g * 8) ^ ((kv & 7) << 3);
                s16x8 bf = *(const s16x8*)(&Klds[kv * 64 + de]);
                sc[0][nt] = __builtin_amdgcn_mfma_f32_16x16x32_bf16(qf[0][ks], bf, sc[0][nt], 0, 0, 0);
                sc[1][nt] = __builtin_amdgcn_mfma_f32_16x16x32_bf16(qf[1][ks], bf, sc[1][nt], 0, 0, 0);
            }
        }

        // ---- online softmax (C rows: r = 4g+reg per mtile) + P -> LDS ----
#pragma unroll
        for (int mt = 0; mt < 2; ++mt)
#pragma unroll
            for (int reg = 0; reg < 4; ++reg) {
                float mx = fmaxf(fmaxf(sc[mt][0][reg], sc[mt][1][reg]),
                                 fmaxf(sc[mt][2][reg], sc[mt][3][reg]));
#pragma unroll
                for (int d_ = 1; d_ <= 8; d_ <<= 1)
                    mx = fmaxf(mx, __shfl_xor(mx, d_));
                float mold = mrun[mt][reg];
                float mnew = fmaxf(mold, mx);
                float alpha = exp2f((mold - mnew) * 1.44269504f);
                int r = mt * 16 + g * 4 + reg;
                float rs = 0.f;
#pragma unroll
                for (int nt = 0; nt < 4; ++nt) {
                    float p = exp2f((sc[mt][nt][reg] - mnew) * 1.44269504f);
                    rs += p;
                    int kv = x + nt * 16;
                    Plds[w * 2048 + r * 64 + (kv ^ ((r & 7) << 3))] = f2bf(p);
                }
#pragma unroll
                for (int d_ = 1; d_ <= 8; d_ <<= 1)
                    rs += __shfl_xor(rs, d_);
                lrun[mt][reg] = lrun[mt][reg] * alpha + rs;
                mrun[mt][reg] = mnew;
#pragma unroll
                for (int nt = 0; nt < 4; ++nt)
                    oacc[mt][nt][reg] *= alpha;
            }

        // ---- O += P V : 16 MFMA ----
#pragma unroll
        for (int ks = 0; ks < 2; ++ks) {
            s16x8 pf[2];
#pragma unroll
            for (int mt = 0; mt < 2; ++mt) {
                int r = mt * 16 + x;
                int kc = (ks * 32 + g * 8) ^ ((r & 7) << 3);
                pf[mt] = *(const s16x8*)(&Plds[w * 2048 + r * 64 + kc]);
            }
#pragma unroll
            for (int nt = 0; nt < 4; ++nt) {
                int d = x + nt * 16;
                int kc = (ks * 32 + g * 8) ^ (((d >> 1) & 7) << 3);
                s16x8 vf = *(const s16x8*)(&Vt[d * 64 + kc]);
                oacc[0][nt] = __builtin_amdgcn_mfma_f32_16x16x32_bf16(pf[0], vf, oacc[0][nt], 0, 0, 0);
                oacc[1][nt] = __builtin_amdgcn_mfma_f32_16x16x32_bf16(pf[1], vf, oacc[1][nt], 0, 0, 0);
            }
        }
    }

    // ---- epilogue: O / l ----
#pragma unroll
    for (int mt = 0; mt < 2; ++mt)
#pragma unroll
        for (int nt = 0; nt < 4; ++nt)
#pragma unroll
            for (int reg = 0; reg < 4; ++reg) {
                int qr = q0 + w * 32 + mt * 16 + g * 4 + reg;
                int d  = x + nt * 16;
                Og[base + (size_t)qr * srow + d] = oacc[mt][nt][reg] / lrun[mt][reg];
            }
}

extern "C" void kernel_launch(void* const* d_in, const int* in_sizes, int n_in,
                              void* d_out, int out_size, void* d_ws, size_t ws_size,
                              hipStream_t stream) {
    const float* Q = (const float*)d_in[0];
    const float* K = (const float*)d_in[1];
    const float* V = (const float*)d_in[2];
    float* O = (float*)d_out;
    usp_attn<<<dim3(512), dim3(256), 0, stream>>>(Q, K, V, O);
}

// Round 5
// 170.563 us; speedup vs baseline: 1.2165x; 1.2165x over previous
//
#include <hip/hip_runtime.h>
#include <hip/hip_bf16.h>
#include <math.h>

typedef float f32x4 __attribute__((ext_vector_type(4)));
typedef short s16x8 __attribute__((ext_vector_type(8)));

#define NS 2048
#define NH 16
#define ND 64
#define QTILE 128
#define KVB 64
#define NT (NS / KVB)
#define L2E 1.44269504f

__device__ __forceinline__ unsigned short f2bf(float f) {
    union { float f; unsigned u; } c; c.f = f;
    return (unsigned short)((c.u + 0x7FFFu + ((c.u >> 16) & 1u)) >> 16);
}
__device__ __forceinline__ unsigned pack2bf(float a, float b) {
    return (unsigned)f2bf(a) | ((unsigned)f2bf(b) << 16);
}

// v3: swapped QK^T (S' = K·Q^T) so softmax rows are lane-local (q = lane&15);
// PV as O^T = V^T·P^T keeps q lane-local for alpha/l. P via packed b64 LDS.
// 8 waves/block (512 thr), 16 q-rows/wave. K/V LDS double-buffered, 1 barrier/tile.
__global__ __launch_bounds__(512, 4)
void usp_attn(const float* __restrict__ Qg, const float* __restrict__ Kg,
              const float* __restrict__ Vg, float* __restrict__ Og) {
    __shared__ unsigned short Klds[2][64 * 64];   // [buf][kv][d]  swz: d ^ ((kv&7)<<3)
    __shared__ unsigned short Vt[2][64 * 64];     // [buf][d][kv]  swz: kv ^ (((d>>1)&7)<<3)
    __shared__ unsigned short Plds[8][16 * 64];   // [wave][q][kv] swz: kv ^ ((q&7)<<3)

    const int tid  = threadIdx.x;
    const int w    = tid >> 6;     // wave 0..7
    const int lane = tid & 63;
    const int g    = lane >> 4;    // 0..3
    const int x    = lane & 15;

    // XCD-chunked swizzle (512 blocks, 8 XCDs, bijective since 512%8==0)
    int bid = blockIdx.x;
    int wg  = (bid & 7) * 64 + (bid >> 3);
    int qt  = wg & 15;
    int bh  = wg >> 4;
    int b   = bh >> 4;
    int h   = bh & 15;
    int q0  = qt * QTILE;

    const int srow = NH * ND;
    const size_t base = ((size_t)b * NS * NH + h) * ND;

    // ---- Q fragment (B-operand): lane (x,g) holds Q[qrow][d=32ks+8g+j], j=0..7 ----
    const int qrow = q0 + w * 16 + x;
    const float* qp = Qg + base + (size_t)qrow * srow;
    s16x8 qf[2];
#pragma unroll
    for (int ks = 0; ks < 2; ++ks) {
        int d0 = ks * 32 + g * 8;
        f32x4 a = *(const f32x4*)(qp + d0);
        f32x4 c = *(const f32x4*)(qp + d0 + 4);
        union { s16x8 v; unsigned u[4]; } r;
        r.u[0] = pack2bf(a[0] * 0.125f, a[1] * 0.125f);
        r.u[1] = pack2bf(a[2] * 0.125f, a[3] * 0.125f);
        r.u[2] = pack2bf(c[0] * 0.125f, c[1] * 0.125f);
        r.u[3] = pack2bf(c[2] * 0.125f, c[3] * 0.125f);
        qf[ks] = r.v;
    }

    f32x4 oacc[4];   // [dt]: O[qrow][d = 16*dt + 4g + reg]
#pragma unroll
    for (int dt = 0; dt < 4; ++dt) oacc[dt] = f32x4{0.f, 0.f, 0.f, 0.f};
    float mrun = -INFINITY, lrun = 0.f;

    // ---- staging: 512 threads, 2 passes cover 64 kv rows x 64 d ----
    const int sub = tid >> 4;          // kv 0..31
    const int c4  = (tid & 15) * 4;    // d column
    const float* kb = Kg + base + (size_t)sub * srow + c4;
    const float* vb = Vg + base + (size_t)sub * srow + c4;

    f32x4 kreg[2], vreg[2];
#define LOADT(t) do { \
        size_t off = (size_t)(t) * KVB * srow; \
        kreg[0] = *(const f32x4*)(kb + off); \
        kreg[1] = *(const f32x4*)(kb + off + (size_t)32 * srow); \
        vreg[0] = *(const f32x4*)(vb + off); \
        vreg[1] = *(const f32x4*)(vb + off + (size_t)32 * srow); \
    } while (0)

#define STORET(bf) do { \
        _Pragma("unroll") \
        for (int p = 0; p < 2; ++p) { \
            int kv = sub + 32 * p; \
            int de = c4 ^ ((kv & 7) << 3); \
            *(uint2*)(&Klds[bf][kv * 64 + de]) = \
                uint2{pack2bf(kreg[p][0], kreg[p][1]), pack2bf(kreg[p][2], kreg[p][3])}; \
            _Pragma("unroll") \
            for (int i = 0; i < 4; ++i) { \
                int d = c4 + i; \
                Vt[bf][d * 64 + (kv ^ (((d >> 1) & 7) << 3))] = f2bf(vreg[p][i]); \
            } \
        } \
    } while (0)

    // prologue: buf0 <- tile0; regs <- tile1
    LOADT(0);
    STORET(0);
    LOADT(1);
    __syncthreads();

    unsigned short* Pw = &Plds[w][0];
    const int rsw = (x & 7) << 3;      // row swizzle for K (kv&7 = x&7) and P (q&7 = x&7)
    const int vsw = (x >> 1) << 3;     // Vt swizzle for d = 16dt + x: (d>>1)&7 = x>>1

    for (int t = 0; t < NT; ++t) {
        const unsigned short* Kc = &Klds[t & 1][0];
        const unsigned short* Vc = &Vt[t & 1][0];

        // write staged regs (tile t+1) into other buffer; prefetch tile t+2
        if (t + 1 < NT) STORET((t + 1) & 1);
        if (t + 2 < NT) LOADT(t + 2);

        // ---- S' = K·Q^T : lane holds S'[kv=16nt+4g+reg][q=qrow] ----
        f32x4 sc[4];
#pragma unroll
        for (int nt = 0; nt < 4; ++nt) sc[nt] = f32x4{0.f, 0.f, 0.f, 0.f};
        __builtin_amdgcn_s_setprio(1);
#pragma unroll
        for (int nt = 0; nt < 4; ++nt) {
            int krow = (16 * nt + x) * 64;
#pragma unroll
            for (int ks = 0; ks < 2; ++ks) {
                s16x8 kf = *(const s16x8*)(&Kc[krow + ((32 * ks + 8 * g) ^ rsw)]);
                sc[nt] = __builtin_amdgcn_mfma_f32_16x16x32_bf16(kf, qf[ks], sc[nt], 0, 0, 0);
            }
        }
        __builtin_amdgcn_s_setprio(0);

        // ---- online softmax, fully lane-local row (q = qrow) ----
        float mx = sc[0][0];
#pragma unroll
        for (int nt = 0; nt < 4; ++nt)
#pragma unroll
            for (int r = 0; r < 4; ++r) mx = fmaxf(mx, sc[nt][r]);
        mx = fmaxf(mx, __shfl_xor(mx, 16));
        mx = fmaxf(mx, __shfl_xor(mx, 32));
        float mnew = fmaxf(mrun, mx);
        float alpha = exp2f((mrun - mnew) * L2E);
        float rs = 0.f;
#pragma unroll
        for (int nt = 0; nt < 4; ++nt) {
#pragma unroll
            for (int r = 0; r < 4; ++r) {
                float p = exp2f((sc[nt][r] - mnew) * L2E);
                sc[nt][r] = p;
                rs += p;
            }
            // packed P write: kv = 16nt+4g .. +3 (b64, swizzled by row x)
            *(uint2*)(&Pw[x * 64 + ((16 * nt + 4 * g) ^ rsw)]) =
                uint2{pack2bf(sc[nt][0], sc[nt][1]), pack2bf(sc[nt][2], sc[nt][3])};
        }
        rs += __shfl_xor(rs, 16);
        rs += __shfl_xor(rs, 32);
        lrun = lrun * alpha + rs;
        mrun = mnew;
#pragma unroll
        for (int dt = 0; dt < 4; ++dt)
#pragma unroll
            for (int r = 0; r < 4; ++r) oacc[dt][r] *= alpha;

        // ---- O^T += V^T · P^T : A = V-frag (row=d), B = P-frag (col=q) ----
        __builtin_amdgcn_s_setprio(1);
#pragma unroll
        for (int ks = 0; ks < 2; ++ks) {
            int k0 = 32 * ks + 8 * g;
            s16x8 pf = *(const s16x8*)(&Pw[x * 64 + (k0 ^ rsw)]);
#pragma unroll
            for (int dt = 0; dt < 4; ++dt) {
                s16x8 vf = *(const s16x8*)(&Vc[(16 * dt + x) * 64 + (k0 ^ vsw)]);
                oacc[dt] = __builtin_amdgcn_mfma_f32_16x16x32_bf16(vf, pf, oacc[dt], 0, 0, 0);
            }
        }
        __builtin_amdgcn_s_setprio(0);

        __syncthreads();
    }

    // ---- epilogue: O[qrow][d] = oacc / lrun ----
    float inv = 1.0f / lrun;
    float* op = Og + base + (size_t)qrow * srow;
#pragma unroll
    for (int dt = 0; dt < 4; ++dt) {
        f32x4 r = oacc[dt];
        r[0] *= inv; r[1] *= inv; r[2] *= inv; r[3] *= inv;
        *(f32x4*)(op + 16 * dt + 4 * g) = r;
    }
}

extern "C" void kernel_launch(void* const* d_in, const int* in_sizes, int n_in,
                              void* d_out, int out_size, void* d_ws, size_t ws_size,
                              hipStream_t stream) {
    const float* Q = (const float*)d_in[0];
    const float* K = (const float*)d_in[1];
    const float* V = (const float*)d_in[2];
    float* O = (float*)d_out;
    usp_attn<<<dim3(512), dim3(512), 0, stream>>>(Q, K, V, O);
}

// Round 7
// 153.897 us; speedup vs baseline: 1.3482x; 1.1083x over previous
//
#include <hip/hip_runtime.h>
#include <hip/hip_bf16.h>
#include <math.h>

typedef float f32x4 __attribute__((ext_vector_type(4)));
typedef short s16x8 __attribute__((ext_vector_type(8)));

#define NS 2048
#define NH 16
#define ND 64
#define QTILE 128
#define KVB 64
#define NT (NS / KVB)
#define QSCALE 0.18033688f   // 0.125 * log2(e): folds 1/sqrt(D) and the exp2 conversion
#define DEFER_THR 11.5f      // log2 units (~e^8): skip O-rescale when max growth small (T13)

// packed f32x2 -> bf16x2 (RNE), single HW instruction (T12 recipe; no builtin on gfx950)
__device__ __forceinline__ unsigned cvtpk(float lo, float hi) {
    unsigned r;
    asm("v_cvt_pk_bf16_f32 %0, %1, %2" : "=v"(r) : "v"(lo), "v"(hi));
    return r;
}

// v4 = v3 structure (swapped QK^T, lane-local softmax, O^T = V^T P^T, 8 waves,
// K/V double-buffer, T14 reg prefetch) + cvt_pk conversions + defer-max + log2e fold.
__global__ __launch_bounds__(512, 4)
void usp_attn(const float* __restrict__ Qg, const float* __restrict__ Kg,
              const float* __restrict__ Vg, float* __restrict__ Og) {
    __shared__ unsigned short Klds[2][64 * 64];   // [buf][kv][d]  swz: d ^ ((kv&7)<<3)
    __shared__ unsigned short Vt[2][64 * 64];     // [buf][d][kv]  swz: kv ^ (((d>>1)&7)<<3)
    __shared__ unsigned short Plds[8][16 * 64];   // [wave][q][kv] swz: kv ^ ((q&7)<<3)

    const int tid  = threadIdx.x;
    const int w    = tid >> 6;     // wave 0..7
    const int lane = tid & 63;
    const int g    = lane >> 4;    // 0..3
    const int x    = lane & 15;

    // XCD-chunked swizzle (512 blocks, 8 XCDs, bijective since 512%8==0)
    int bid = blockIdx.x;
    int wg  = (bid & 7) * 64 + (bid >> 3);
    int qt  = wg & 15;
    int bh  = wg >> 4;
    int b   = bh >> 4;
    int h   = bh & 15;
    int q0  = qt * QTILE;

    const int srow = NH * ND;
    const size_t base = ((size_t)b * NS * NH + h) * ND;

    // ---- Q fragment (B-operand): lane (x,g) holds Q[qrow][d=32ks+8g+j], j=0..7 ----
    const int qrow = q0 + w * 16 + x;
    const float* qp = Qg + base + (size_t)qrow * srow;
    s16x8 qf[2];
#pragma unroll
    for (int ks = 0; ks < 2; ++ks) {
        int d0 = ks * 32 + g * 8;
        f32x4 a = *(const f32x4*)(qp + d0);
        f32x4 c = *(const f32x4*)(qp + d0 + 4);
        union { s16x8 v; unsigned u[4]; } r;
        r.u[0] = cvtpk(a[0] * QSCALE, a[1] * QSCALE);
        r.u[1] = cvtpk(a[2] * QSCALE, a[3] * QSCALE);
        r.u[2] = cvtpk(c[0] * QSCALE, c[1] * QSCALE);
        r.u[3] = cvtpk(c[2] * QSCALE, c[3] * QSCALE);
        qf[ks] = r.v;
    }

    f32x4 oacc[4];   // [dt]: O[qrow][d = 16*dt + 4g + reg]
#pragma unroll
    for (int dt = 0; dt < 4; ++dt) oacc[dt] = f32x4{0.f, 0.f, 0.f, 0.f};
    float mrun = -INFINITY, lrun = 0.f;

    // ---- staging: 512 threads, 2 passes cover 64 kv rows x 64 d ----
    const int sub = tid >> 4;          // kv 0..31
    const int c4  = (tid & 15) * 4;    // d column
    const float* kb = Kg + base + (size_t)sub * srow + c4;
    const float* vb = Vg + base + (size_t)sub * srow + c4;

    f32x4 kreg[2], vreg[2];
#define LOADT(t) do { \
        size_t off = (size_t)(t) * KVB * srow; \
        kreg[0] = *(const f32x4*)(kb + off); \
        kreg[1] = *(const f32x4*)(kb + off + (size_t)32 * srow); \
        vreg[0] = *(const f32x4*)(vb + off); \
        vreg[1] = *(const f32x4*)(vb + off + (size_t)32 * srow); \
    } while (0)

    // Vt swizzles: d0..d0+1 share (d>>1), d0+2..d0+3 use (d>>1)+1  (c4 % 4 == 0)
#define STORET(bf) do { \
        _Pragma("unroll") \
        for (int p = 0; p < 2; ++p) { \
            int kv = sub + 32 * p; \
            int de = c4 ^ ((kv & 7) << 3); \
            *(uint2*)(&Klds[bf][kv * 64 + de]) = \
                uint2{cvtpk(kreg[p][0], kreg[p][1]), cvtpk(kreg[p][2], kreg[p][3])}; \
            unsigned va = cvtpk(vreg[p][0], vreg[p][1]); \
            unsigned vb2 = cvtpk(vreg[p][2], vreg[p][3]); \
            int s01 = kv ^ (((c4 >> 1) & 7) << 3); \
            int s23 = kv ^ ((((c4 >> 1) + 1) & 7) << 3); \
            Vt[bf][(c4 + 0) * 64 + s01] = (unsigned short)va; \
            Vt[bf][(c4 + 1) * 64 + s01] = (unsigned short)(va >> 16); \
            Vt[bf][(c4 + 2) * 64 + s23] = (unsigned short)vb2; \
            Vt[bf][(c4 + 3) * 64 + s23] = (unsigned short)(vb2 >> 16); \
        } \
    } while (0)

    // prologue: buf0 <- tile0; regs <- tile1
    LOADT(0);
    STORET(0);
    LOADT(1);
    __syncthreads();

    unsigned short* Pw = &Plds[w][0];
    const int rsw = (x & 7) << 3;      // row swizzle for K (kv&7 = x&7) and P (q&7 = x&7)
    const int vsw = (x >> 1) << 3;     // Vt swizzle for d = 16dt + x: (d>>1)&7 = x>>1

    for (int t = 0; t < NT; ++t) {
        const unsigned short* Kc = &Klds[t & 1][0];
        const unsigned short* Vc = &Vt[t & 1][0];

        // write staged regs (tile t+1) into other buffer; prefetch tile t+2 (T14)
        if (t + 1 < NT) STORET((t + 1) & 1);
        if (t + 2 < NT) LOADT(t + 2);

        // ---- S' = K·Q^T (log2-units) : lane holds S'[kv=16nt+4g+reg][q=qrow] ----
        f32x4 sc[4];
#pragma unroll
        for (int nt = 0; nt < 4; ++nt) sc[nt] = f32x4{0.f, 0.f, 0.f, 0.f};
        __builtin_amdgcn_s_setprio(1);
#pragma unroll
        for (int nt = 0; nt < 4; ++nt) {
            int krow = (16 * nt + x) * 64;
#pragma unroll
            for (int ks = 0; ks < 2; ++ks) {
                s16x8 kf = *(const s16x8*)(&Kc[krow + ((32 * ks + 8 * g) ^ rsw)]);
                sc[nt] = __builtin_amdgcn_mfma_f32_16x16x32_bf16(kf, qf[ks], sc[nt], 0, 0, 0);
            }
        }
        __builtin_amdgcn_s_setprio(0);

        // ---- online softmax, lane-local rows; T13 defer-max ----
        float mx = sc[0][0];
#pragma unroll
        for (int nt = 0; nt < 4; ++nt)
#pragma unroll
            for (int r = 0; r < 4; ++r) mx = fmaxf(mx, sc[nt][r]);
        mx = fmaxf(mx, __shfl_xor(mx, 16));
        mx = fmaxf(mx, __shfl_xor(mx, 32));
        if (!__all(mx - mrun <= DEFER_THR)) {
            float mnew = fmaxf(mrun, mx);
            float alpha = exp2f(mrun - mnew);   // log2 units
            mrun = mnew;
            lrun *= alpha;
#pragma unroll
            for (int dt = 0; dt < 4; ++dt)
#pragma unroll
                for (int r = 0; r < 4; ++r) oacc[dt][r] *= alpha;
        }
        float rs = 0.f;
#pragma unroll
        for (int nt = 0; nt < 4; ++nt) {
            float p0 = exp2f(sc[nt][0] - mrun);
            float p1 = exp2f(sc[nt][1] - mrun);
            float p2 = exp2f(sc[nt][2] - mrun);
            float p3 = exp2f(sc[nt][3] - mrun);
            rs += (p0 + p1) + (p2 + p3);
            *(uint2*)(&Pw[x * 64 + ((16 * nt + 4 * g) ^ rsw)]) =
                uint2{cvtpk(p0, p1), cvtpk(p2, p3)};
        }
        rs += __shfl_xor(rs, 16);
        rs += __shfl_xor(rs, 32);
        lrun += rs;

        // ---- O^T += V^T · P^T : A = V-frag (row=d), B = P-frag (col=q) ----
        __builtin_amdgcn_s_setprio(1);
#pragma unroll
        for (int ks = 0; ks < 2; ++ks) {
            int k0 = 32 * ks + 8 * g;
            s16x8 pf = *(const s16x8*)(&Pw[x * 64 + (k0 ^ rsw)]);
#pragma unroll
            for (int dt = 0; dt < 4; ++dt) {
                s16x8 vf = *(const s16x8*)(&Vc[(16 * dt + x) * 64 + (k0 ^ vsw)]);
                oacc[dt] = __builtin_amdgcn_mfma_f32_16x16x32_bf16(vf, pf, oacc[dt], 0, 0, 0);
            }
        }
        __builtin_amdgcn_s_setprio(0);

        __syncthreads();
    }

    // ---- epilogue: O[qrow][d] = oacc / lrun ----
    float inv = 1.0f / lrun;
    float* op = Og + base + (size_t)qrow * srow;
#pragma unroll
    for (int dt = 0; dt < 4; ++dt) {
        f32x4 r = oacc[dt];
        r[0] *= inv; r[1] *= inv; r[2] *= inv; r[3] *= inv;
        *(f32x4*)(op + 16 * dt + 4 * g) = r;
    }
}

extern "C" void kernel_launch(void* const* d_in, const int* in_sizes, int n_in,
                              void* d_out, int out_size, void* d_ws, size_t ws_size,
                              hipStream_t stream) {
    const float* Q = (const float*)d_in[0];
    const float* K = (const float*)d_in[1];
    const float* V = (const float*)d_in[2];
    float* O = (float*)d_out;
    usp_attn<<<dim3(512), dim3(512), 0, stream>>>(Q, K, V, O);
}